// Round 1
// baseline (430.215 us; speedup 1.0000x reference)
//
#include <hip/hip_runtime.h>

// Problem constants (from reference)
#define Bn   256
#define Cc   7
#define Nn   16384        // H*W = 128*128
#define HIDW 256
#define SEL  3
#define Mrows (Bn * Cc)   // 1792
#define KSPLIT 8
#define KCHUNK (Nn / KSPLIT)  // 2048

// ---------------------------------------------------------------------------
// K1: split-K fp32 GEMM  hid[M][HIDW] += feat[M][K] @ w1[K][HIDW]
//     64x64 tile / block, 256 threads, 4x4 micro-tile, K-chunk 2048.
//     Atomic accumulate (hid zero-initialized by memset; bias added in K2).
// ---------------------------------------------------------------------------
__global__ __launch_bounds__(256) void gemm_splitk(const float* __restrict__ A,
                                                   const float* __restrict__ Bw,
                                                   float* __restrict__ hid) {
    // As stored transposed [k][m], row stride 68 floats (272 B = 16B-aligned,
    // breaks pow2 bank stride). Bs natural [k][n].
    __shared__ float As[16][68];
    __shared__ float Bs[16][64];

    const int n0 = blockIdx.x * 64;
    const int m0 = blockIdx.y * 64;
    const int k0 = blockIdx.z * KCHUNK;
    const int t  = threadIdx.x;
    const int tx = t & 15;   // N direction
    const int ty = t >> 4;   // M direction

    // staging load mapping
    const int ar  = t >> 2;          // A row 0..63
    const int ac4 = (t & 3) << 2;    // A k-offset 0..12
    const int bk  = t >> 4;          // B k 0..15
    const int bn4 = (t & 15) << 2;   // B n-offset 0..60

    float acc[4][4] = {};

    const float* aptr = A + (m0 + ar) * Nn + ac4;
    const float* bptr = Bw + bk * HIDW + n0 + bn4;

    for (int kk = k0; kk < k0 + KCHUNK; kk += 16) {
        float4 av = *(const float4*)(aptr + kk);
        float4 bv = *(const float4*)(bptr + kk * HIDW);
        __syncthreads();   // previous iteration's LDS reads done
        As[ac4 + 0][ar] = av.x;
        As[ac4 + 1][ar] = av.y;
        As[ac4 + 2][ar] = av.z;
        As[ac4 + 3][ar] = av.w;
        *(float4*)&Bs[bk][bn4] = bv;
        __syncthreads();
#pragma unroll
        for (int k = 0; k < 16; ++k) {
            float4 a = *(const float4*)(&As[k][ty * 4]);
            float4 b = *(const float4*)(&Bs[k][tx * 4]);
            float av4[4] = {a.x, a.y, a.z, a.w};
            float bv4[4] = {b.x, b.y, b.z, b.w};
#pragma unroll
            for (int i = 0; i < 4; ++i)
#pragma unroll
                for (int j = 0; j < 4; ++j)
                    acc[i][j] = fmaf(av4[i], bv4[j], acc[i][j]);
        }
    }

#pragma unroll
    for (int i = 0; i < 4; ++i)
#pragma unroll
        for (int j = 0; j < 4; ++j)
            atomicAdd(&hid[(m0 + ty * 4 + i) * HIDW + (n0 + tx * 4 + j)], acc[i][j]);
}

// ---------------------------------------------------------------------------
// K2: scores[row] = relu(hid[row][:] + b1) . w2 + b2   (one block per row)
// ---------------------------------------------------------------------------
__global__ __launch_bounds__(256) void score_kernel(const float* __restrict__ hid,
                                                    const float* __restrict__ b1,
                                                    const float* __restrict__ w2,
                                                    const float* __restrict__ b2,
                                                    float* __restrict__ scores) {
    const int row = blockIdx.x;
    const int t   = threadIdx.x;
    float h = hid[row * HIDW + t] + b1[t];
    h = fmaxf(h, 0.0f);
    float p = h * w2[t];
#pragma unroll
    for (int off = 32; off > 0; off >>= 1) p += __shfl_down(p, off, 64);
    __shared__ float partial[4];
    if ((t & 63) == 0) partial[t >> 6] = p;
    __syncthreads();
    if (t == 0)
        scores[row] = partial[0] + partial[1] + partial[2] + partial[3] + b2[0];
}

// ---------------------------------------------------------------------------
// K3: per batch: top-3 of 7 scores (ties -> lower index, matching lax.top_k),
//     write indices (as float) and gather selected bands of x.
// ---------------------------------------------------------------------------
__global__ __launch_bounds__(256) void topk_gather(const float* __restrict__ x,
                                                   const float* __restrict__ scores,
                                                   float* __restrict__ out) {
    const int b = blockIdx.x;
    __shared__ int sidx[SEL];
    if (threadIdx.x == 0) {
        float s[Cc];
#pragma unroll
        for (int c = 0; c < Cc; ++c) s[c] = scores[b * Cc + c];
        bool used[Cc] = {};
#pragma unroll
        for (int k = 0; k < SEL; ++k) {
            int best = 0;
            float bv = -3.4e38f;
#pragma unroll
            for (int c = 0; c < Cc; ++c) {
                if (!used[c] && s[c] > bv) { bv = s[c]; best = c; }
            }
            used[best] = true;
            sidx[k] = best;
            // indices live after the selected tensor, stored as float values
            out[(size_t)Bn * SEL * Nn + b * SEL + k] = (float)best;
        }
    }
    __syncthreads();
#pragma unroll
    for (int k = 0; k < SEL; ++k) {
        const float4* src = (const float4*)(x + (size_t)(b * Cc + sidx[k]) * Nn);
        float4* dst = (float4*)(out + (size_t)(b * SEL + k) * Nn);
        for (int i = threadIdx.x; i < Nn / 4; i += 256) dst[i] = src[i];
    }
}

// ---------------------------------------------------------------------------
extern "C" void kernel_launch(void* const* d_in, const int* in_sizes, int n_in,
                              void* d_out, int out_size, void* d_ws, size_t ws_size,
                              hipStream_t stream) {
    const float* x  = (const float*)d_in[0];
    // d_in[1] = w_qkv, d_in[2] = b_qkv: dead code in the reference forward
    const float* w1 = (const float*)d_in[3];
    const float* b1 = (const float*)d_in[4];
    const float* w2 = (const float*)d_in[5];
    const float* b2 = (const float*)d_in[6];
    float* out = (float*)d_out;

    float* hid    = (float*)d_ws;                 // Mrows * HIDW floats
    float* scores = hid + (size_t)Mrows * HIDW;   // Mrows floats

    // zero the atomic-accumulated hid buffer (ws is poisoned 0xAA each call)
    hipMemsetAsync(hid, 0, (size_t)Mrows * HIDW * sizeof(float), stream);

    gemm_splitk<<<dim3(HIDW / 64, Mrows / 64, KSPLIT), 256, 0, stream>>>(x, w1, hid);
    score_kernel<<<Mrows, 256, 0, stream>>>(hid, b1, w2, b2, scores);
    topk_gather<<<Bn, 256, 0, stream>>>(x, scores, out);
}

// Round 2
// 418.525 us; speedup vs baseline: 1.0279x; 1.0279x over previous
//
#include <hip/hip_runtime.h>

// Problem constants
#define Bn    256
#define Cc    7
#define Nn    16384          // H*W
#define HIDW  256
#define SEL   3
#define Mrows (Bn * Cc)      // 1792
#define KSPLIT 32
#define KCHUNK (Nn / KSPLIT) // 512
#define BK    16
#define PART_STRIDE ((size_t)Mrows * HIDW)   // floats per k-split slice

// ---------------------------------------------------------------------------
// K1: fp32 GEMM  part[s][M][256] = feat[M][Kslice] @ w1[Kslice][256]
//     128x128 tile, 256 threads, 8x8 micro-tile, BK=16.
//     B LDS uses a +4-float skew per 32 cols -> b128 reads are 2-way (free).
//     atomic==false: plain stores to slice s. atomic==true: atomicAdd slice 0.
// ---------------------------------------------------------------------------
__global__ __launch_bounds__(256, 4) void gemm_splitk(const float* __restrict__ A,
                                                      const float* __restrict__ Bw,
                                                      float* __restrict__ part,
                                                      int atomic) {
    __shared__ float As[BK][136];   // [k][m], conflict-free (banks 0,8,16,24)
    __shared__ float Bs[BK][140];   // [k][skewed n]

    const int n0 = blockIdx.x * 128;
    const int m0 = blockIdx.y * 128;
    const int s  = blockIdx.z;
    const int k0 = s * KCHUNK;
    const int t  = threadIdx.x;
    const int tx = t & 15;          // N micro index
    const int ty = t >> 4;          // M micro index

    // A staging mapping: thread loads 8 consecutive k's of one row
    const int ar  = t >> 1;         // row 0..127
    const int ak8 = (t & 1) << 3;   // k offset 0 or 8
    // B staging mapping: two float4s, f = t and t+256
    const int bk  = t >> 5;         // k row 0..7 (second is +8)
    const int bn4 = (t & 31) << 2;  // col 0..124
    const int bpw = bn4 + ((bn4 >> 5) << 2);  // skewed write col

    const int nB = tx * 8;
    const int pB = nB + ((nB >> 5) << 2);     // skewed read col

    float acc[8][8] = {};

    const float* aptr = A + (size_t)(m0 + ar) * Nn + k0 + ak8;
    const float* bptr = Bw + (size_t)(k0 + bk) * HIDW + n0 + bn4;

    for (int kk = 0; kk < KCHUNK; kk += BK) {
        float4 av0 = *(const float4*)(aptr + kk);
        float4 av1 = *(const float4*)(aptr + kk + 4);
        float4 bv0 = *(const float4*)(bptr + (size_t)kk * HIDW);
        float4 bv1 = *(const float4*)(bptr + (size_t)(kk + 8) * HIDW);
        __syncthreads();
        As[ak8 + 0][ar] = av0.x;  As[ak8 + 1][ar] = av0.y;
        As[ak8 + 2][ar] = av0.z;  As[ak8 + 3][ar] = av0.w;
        As[ak8 + 4][ar] = av1.x;  As[ak8 + 5][ar] = av1.y;
        As[ak8 + 6][ar] = av1.z;  As[ak8 + 7][ar] = av1.w;
        *(float4*)&Bs[bk][bpw]     = bv0;
        *(float4*)&Bs[bk + 8][bpw] = bv1;
        __syncthreads();
#pragma unroll
        for (int k = 0; k < BK; ++k) {
            float4 a0 = *(const float4*)&As[k][ty * 8];
            float4 a1 = *(const float4*)&As[k][ty * 8 + 4];
            float4 b0 = *(const float4*)&Bs[k][pB];
            float4 b1 = *(const float4*)&Bs[k][pB + 4];
            float av[8] = {a0.x, a0.y, a0.z, a0.w, a1.x, a1.y, a1.z, a1.w};
            float bv[8] = {b0.x, b0.y, b0.z, b0.w, b1.x, b1.y, b1.z, b1.w};
#pragma unroll
            for (int i = 0; i < 8; ++i)
#pragma unroll
                for (int j = 0; j < 8; ++j)
                    acc[i][j] = fmaf(av[i], bv[j], acc[i][j]);
        }
    }

    if (atomic) {
#pragma unroll
        for (int i = 0; i < 8; ++i) {
            float* dst = part + (size_t)(m0 + ty * 8 + i) * HIDW + n0 + tx * 8;
#pragma unroll
            for (int j = 0; j < 8; ++j) atomicAdd(dst + j, acc[i][j]);
        }
    } else {
        float* base = part + (size_t)s * PART_STRIDE;
#pragma unroll
        for (int i = 0; i < 8; ++i) {
            float* dst = base + (size_t)(m0 + ty * 8 + i) * HIDW + n0 + tx * 8;
            *(float4*)dst       = make_float4(acc[i][0], acc[i][1], acc[i][2], acc[i][3]);
            *(float4*)(dst + 4) = make_float4(acc[i][4], acc[i][5], acc[i][6], acc[i][7]);
        }
    }
}

// ---------------------------------------------------------------------------
// K2 (fused tail): per batch — reduce k-split partials, relu+dot w2 -> 7
// scores, top-3, write indices, gather 3 bands.
// ---------------------------------------------------------------------------
__global__ __launch_bounds__(256) void tail_kernel(const float* __restrict__ part,
                                                   const float* __restrict__ x,
                                                   const float* __restrict__ b1,
                                                   const float* __restrict__ w2,
                                                   const float* __restrict__ b2,
                                                   float* __restrict__ out,
                                                   int nparts) {
    const int b = blockIdx.x;
    const int t = threadIdx.x;
    __shared__ float red[4];
    __shared__ float sc[Cc];
    __shared__ int   sidx[SEL];

    const float bias = b1[t];
    const float wv   = w2[t];

    for (int c = 0; c < Cc; ++c) {
        const size_t row = (size_t)(b * Cc + c) * HIDW + t;
        float h = 0.0f;
        for (int s = 0; s < nparts; ++s) h += part[(size_t)s * PART_STRIDE + row];
        float p = fmaxf(h + bias, 0.0f) * wv;
#pragma unroll
        for (int off = 32; off > 0; off >>= 1) p += __shfl_down(p, off, 64);
        if ((t & 63) == 0) red[t >> 6] = p;
        __syncthreads();
        if (t == 0) sc[c] = red[0] + red[1] + red[2] + red[3] + b2[0];
        __syncthreads();
    }

    if (t == 0) {
        bool used[Cc] = {};
#pragma unroll
        for (int k = 0; k < SEL; ++k) {
            int best = 0;
            float bv = -3.4e38f;
#pragma unroll
            for (int c = 0; c < Cc; ++c)
                if (!used[c] && sc[c] > bv) { bv = sc[c]; best = c; }
            used[best] = true;
            sidx[k] = best;
            out[(size_t)Bn * SEL * Nn + b * SEL + k] = (float)best;
        }
    }
    __syncthreads();

#pragma unroll
    for (int k = 0; k < SEL; ++k) {
        const float4* src = (const float4*)(x + (size_t)(b * Cc + sidx[k]) * Nn);
        float4* dst = (float4*)(out + (size_t)(b * SEL + k) * Nn);
        for (int i = t; i < Nn / 4; i += 256) dst[i] = src[i];
    }
}

// ---------------------------------------------------------------------------
extern "C" void kernel_launch(void* const* d_in, const int* in_sizes, int n_in,
                              void* d_out, int out_size, void* d_ws, size_t ws_size,
                              hipStream_t stream) {
    const float* x  = (const float*)d_in[0];
    // d_in[1]=w_qkv, d_in[2]=b_qkv: dead in the reference forward
    const float* w1 = (const float*)d_in[3];
    const float* b1 = (const float*)d_in[4];
    const float* w2 = (const float*)d_in[5];
    const float* b2 = (const float*)d_in[6];
    float* out = (float*)d_out;

    float* part = (float*)d_ws;
    const size_t need = (size_t)KSPLIT * PART_STRIDE * sizeof(float);  // ~58.7 MB

    if (ws_size >= need) {
        // preferred: plain stores per k-split, no memset, no atomics
        gemm_splitk<<<dim3(HIDW / 128, Mrows / 128, KSPLIT), 256, 0, stream>>>(x, w1, part, 0);
        tail_kernel<<<Bn, 256, 0, stream>>>(part, x, b1, w2, b2, out, KSPLIT);
    } else {
        // fallback: atomics into a single slice
        hipMemsetAsync(part, 0, PART_STRIDE * sizeof(float), stream);
        gemm_splitk<<<dim3(HIDW / 128, Mrows / 128, KSPLIT), 256, 0, stream>>>(x, w1, part, 1);
        tail_kernel<<<Bn, 256, 0, stream>>>(part, x, b1, w2, b2, out, 1);
    }
}

// Round 3
// 266.139 us; speedup vs baseline: 1.6165x; 1.5726x over previous
//
#include <hip/hip_runtime.h>

#define Bn    256
#define Cc    7
#define Nn    16384
#define HIDW  256
#define SEL   3
#define Mrows (Bn * Cc)            // 1792
#define KSPLIT 16
#define KCHUNK (Nn / KSPLIT)       // 1024
#define BK    32
#define PART_STRIDE ((size_t)Mrows * HIDW)   // floats per k-split slice

typedef __attribute__((ext_vector_type(8))) short bf16x8;
typedef __attribute__((ext_vector_type(4))) float floatx4;

__device__ __forceinline__ unsigned short bf16_rne(float f) {
    unsigned int u = __float_as_uint(f);
    unsigned int r = u + 0x7fffu + ((u >> 16) & 1u);
    return (unsigned short)(r >> 16);
}

__device__ __forceinline__ uint4 pack8(const unsigned short* p) {
    uint4 v;
    v.x = (unsigned)p[0] | ((unsigned)p[1] << 16);
    v.y = (unsigned)p[2] | ((unsigned)p[3] << 16);
    v.z = (unsigned)p[4] | ((unsigned)p[5] << 16);
    v.w = (unsigned)p[6] | ((unsigned)p[7] << 16);
    return v;
}

// ---------------------------------------------------------------------------
// K0: convert w1[k][n] (fp32) -> fragment-ordered bf16 hi/lo planes.
// Chunk layout: chunk(c,T,lane) holds B[k = c*32 + (lane>>4)*8 + j][n = T*16
// + (lane&15)], j=0..7, at ushort offset ((c*16+T)*64 + lane)*8.
// ---------------------------------------------------------------------------
__global__ __launch_bounds__(256) void convert_w1(const float* __restrict__ w1,
                                                  unsigned short* __restrict__ bhi,
                                                  unsigned short* __restrict__ blo) {
    const int id = blockIdx.x * 256 + threadIdx.x;   // 0 .. 512*16*64-1
    const int l  = id & 63;
    const int ct = id >> 6;
    const int T  = ct & 15;
    const int c  = ct >> 4;
    const int n  = T * 16 + (l & 15);
    const int k  = c * 32 + (l >> 4) * 8;
    unsigned short hi[8], lo[8];
#pragma unroll
    for (int j = 0; j < 8; ++j) {
        float f = w1[(size_t)(k + j) * HIDW + n];
        unsigned short h = bf16_rne(f);
        float fh = __uint_as_float((unsigned)h << 16);
        hi[j] = h;
        lo[j] = bf16_rne(f - fh);
    }
    *(uint4*)(bhi + (size_t)id * 8) = pack8(hi);
    *(uint4*)(blo + (size_t)id * 8) = pack8(lo);
}

// ---------------------------------------------------------------------------
// K1: MFMA GEMM  part[s][M][256] = feat[M][Kslice] @ w1[Kslice][256]
//     128x128 tile, 256 thr (4 waves, 2x2), 16x16x32 bf16 MFMA,
//     2-term bf16 split (3 MFMA passes, fp32 accumulate).
// ---------------------------------------------------------------------------
__global__ __launch_bounds__(256) void gemm_mfma(const float* __restrict__ A,
                                                 const unsigned short* __restrict__ Bhi,
                                                 const unsigned short* __restrict__ Blo,
                                                 float* __restrict__ part) {
    __shared__ unsigned short Ah[4096], Al[4096], Bh[4096], Bl[4096];  // 8 KB each

    const int bx = blockIdx.x;          // n-tile (0..1), n0 = bx*128
    const int m0 = blockIdx.y * 128;
    const int s  = blockIdx.z;
    const int k0 = s * KCHUNK;
    const int t  = threadIdx.x;
    const int lane = t & 63;
    const int w    = t >> 6;
    const int wm   = w & 1;             // wave M quadrant
    const int wn   = w >> 1;            // wave N quadrant

    // A staging: thread t loads 16 consecutive k's of row ar
    const int ar  = t >> 1;             // 0..127
    const int kof = (t & 1) * 16;       // 0 or 16
    const float* aptr = A + (size_t)(m0 + ar) * Nn + k0 + kof;
    // fragment-order LDS ushort indices for the two 8-k chunks this thread owns
    const int aidx0 = (ar >> 4) * 512 + ((ar & 15) + ((kof >> 3) + 0) * 16) * 8;
    const int aidx1 = (ar >> 4) * 512 + ((ar & 15) + ((kof >> 3) + 1) * 16) * 8;

    floatx4 acc[4][4];
#pragma unroll
    for (int i = 0; i < 4; ++i)
#pragma unroll
        for (int j = 0; j < 4; ++j) acc[i][j] = (floatx4)0.0f;

    for (int kk = 0; kk < KCHUNK; kk += BK) {
        // ---- global loads ----
        float4 a0 = *(const float4*)(aptr + kk + 0);
        float4 a1 = *(const float4*)(aptr + kk + 4);
        float4 a2 = *(const float4*)(aptr + kk + 8);
        float4 a3 = *(const float4*)(aptr + kk + 12);
        const size_t bbase = ((size_t)(((k0 + kk) >> 5) * 16 + bx * 8)) * 512;
        uint4 bh0 = *(const uint4*)(Bhi + bbase + t * 8);
        uint4 bh1 = *(const uint4*)(Bhi + bbase + 2048 + t * 8);
        uint4 bl0 = *(const uint4*)(Blo + bbase + t * 8);
        uint4 bl1 = *(const uint4*)(Blo + bbase + 2048 + t * 8);

        // ---- convert A to hi/lo ----
        float af[16] = {a0.x, a0.y, a0.z, a0.w, a1.x, a1.y, a1.z, a1.w,
                        a2.x, a2.y, a2.z, a2.w, a3.x, a3.y, a3.z, a3.w};
        unsigned short hi[16], lo[16];
#pragma unroll
        for (int j = 0; j < 16; ++j) {
            unsigned short h = bf16_rne(af[j]);
            hi[j] = h;
            lo[j] = bf16_rne(af[j] - __uint_as_float((unsigned)h << 16));
        }

        __syncthreads();   // previous iteration's frag reads complete
        *(uint4*)&Ah[aidx0] = pack8(hi);
        *(uint4*)&Ah[aidx1] = pack8(hi + 8);
        *(uint4*)&Al[aidx0] = pack8(lo);
        *(uint4*)&Al[aidx1] = pack8(lo + 8);
        *(uint4*)&Bh[t * 8]        = bh0;
        *(uint4*)&Bh[2048 + t * 8] = bh1;
        *(uint4*)&Bl[t * 8]        = bl0;
        *(uint4*)&Bl[2048 + t * 8] = bl1;
        __syncthreads();

        // ---- fragments + MFMA ----
        bf16x8 fah[4], fal[4], fbh[4], fbl[4];
#pragma unroll
        for (int i = 0; i < 4; ++i) {
            fah[i] = *(const bf16x8*)&Ah[(wm * 4 + i) * 512 + lane * 8];
            fal[i] = *(const bf16x8*)&Al[(wm * 4 + i) * 512 + lane * 8];
        }
#pragma unroll
        for (int j = 0; j < 4; ++j) {
            fbh[j] = *(const bf16x8*)&Bh[(wn * 4 + j) * 512 + lane * 8];
            fbl[j] = *(const bf16x8*)&Bl[(wn * 4 + j) * 512 + lane * 8];
        }
#pragma unroll
        for (int i = 0; i < 4; ++i)
#pragma unroll
            for (int j = 0; j < 4; ++j) {
                acc[i][j] = __builtin_amdgcn_mfma_f32_16x16x32_bf16(fah[i], fbh[j], acc[i][j], 0, 0, 0);
                acc[i][j] = __builtin_amdgcn_mfma_f32_16x16x32_bf16(fah[i], fbl[j], acc[i][j], 0, 0, 0);
                acc[i][j] = __builtin_amdgcn_mfma_f32_16x16x32_bf16(fal[i], fbh[j], acc[i][j], 0, 0, 0);
            }
    }

    // ---- epilogue: C/D layout col=lane&15, row=(lane>>4)*4+reg ----
    const int row4 = (lane >> 4) * 4;
    const int col  = lane & 15;
    float* base = part + (size_t)s * PART_STRIDE;
#pragma unroll
    for (int i = 0; i < 4; ++i)
#pragma unroll
        for (int j = 0; j < 4; ++j) {
            const int n = bx * 128 + wn * 64 + j * 16 + col;
#pragma unroll
            for (int p = 0; p < 4; ++p) {
                const int m = m0 + wm * 64 + i * 16 + row4 + p;
                base[(size_t)m * HIDW + n] = acc[i][j][p];
            }
        }
}

// ---------------------------------------------------------------------------
// K2: per batch — reduce KSPLIT partials (compile-time unrolled), relu+dot w2,
//     top-3, write index floats + sidx for gather.
// ---------------------------------------------------------------------------
__global__ __launch_bounds__(256) void score_topk(const float* __restrict__ part,
                                                  const float* __restrict__ b1,
                                                  const float* __restrict__ w2,
                                                  const float* __restrict__ b2,
                                                  float* __restrict__ out,
                                                  int* __restrict__ sidx) {
    const int b = blockIdx.x;
    const int t = threadIdx.x;
    __shared__ float red[4];
    __shared__ float sc[Cc];
    const float bias = b1[t];
    const float wv   = w2[t];

    for (int c = 0; c < Cc; ++c) {
        const size_t row = (size_t)(b * Cc + c) * HIDW + t;
        float h = 0.0f;
#pragma unroll
        for (int s2 = 0; s2 < KSPLIT; ++s2) h += part[(size_t)s2 * PART_STRIDE + row];
        float p = fmaxf(h + bias, 0.0f) * wv;
#pragma unroll
        for (int off = 32; off > 0; off >>= 1) p += __shfl_down(p, off, 64);
        if ((t & 63) == 0) red[t >> 6] = p;
        __syncthreads();
        if (t == 0) sc[c] = red[0] + red[1] + red[2] + red[3] + b2[0];
        __syncthreads();
    }

    if (t == 0) {
        bool used[Cc] = {};
#pragma unroll
        for (int k = 0; k < SEL; ++k) {
            int best = 0;
            float bv = -3.4e38f;
#pragma unroll
            for (int c = 0; c < Cc; ++c)
                if (!used[c] && sc[c] > bv) { bv = sc[c]; best = c; }
            used[best] = true;
            sidx[b * SEL + k] = best;
            out[(size_t)Bn * SEL * Nn + b * SEL + k] = (float)best;
        }
    }
}

// ---------------------------------------------------------------------------
// K3: gather — one block per (batch, k): copy selected band.
// ---------------------------------------------------------------------------
__global__ __launch_bounds__(256) void gather_bands(const float* __restrict__ x,
                                                    const int* __restrict__ sidx,
                                                    float* __restrict__ out) {
    const int id = blockIdx.x;           // 0 .. Bn*SEL-1
    const int b  = id / SEL;
    const int band = sidx[id];
    const float4* src = (const float4*)(x + (size_t)(b * Cc + band) * Nn);
    float4* dst = (float4*)(out + (size_t)id * Nn);
    for (int i = threadIdx.x; i < Nn / 4; i += 256) dst[i] = src[i];
}

// ---------------------------------------------------------------------------
extern "C" void kernel_launch(void* const* d_in, const int* in_sizes, int n_in,
                              void* d_out, int out_size, void* d_ws, size_t ws_size,
                              hipStream_t stream) {
    const float* x  = (const float*)d_in[0];
    // d_in[1]=w_qkv, d_in[2]=b_qkv: dead in the reference forward
    const float* w1 = (const float*)d_in[3];
    const float* b1 = (const float*)d_in[4];
    const float* w2 = (const float*)d_in[5];
    const float* b2 = (const float*)d_in[6];
    float* out = (float*)d_out;

    char* ws = (char*)d_ws;
    float* part = (float*)ws;                                   // 29.36 MB
    unsigned short* bhi = (unsigned short*)(ws + KSPLIT * PART_STRIDE * sizeof(float));
    unsigned short* blo = bhi + (size_t)Nn * HIDW;              // 8 MB each
    int* sidx = (int*)(blo + (size_t)Nn * HIDW);                // 3 KB

    convert_w1<<<(Nn / 32) * 16 * 64 / 256, 256, 0, stream>>>(w1, bhi, blo);
    gemm_mfma<<<dim3(HIDW / 128, Mrows / 128, KSPLIT), 256, 0, stream>>>(x, bhi, blo, part);
    score_topk<<<Bn, 256, 0, stream>>>(part, b1, w2, b2, out, sidx);
    gather_bands<<<Bn * SEL, 256, 0, stream>>>(x, sidx, out);
}

// Round 4
// 263.542 us; speedup vs baseline: 1.6324x; 1.0099x over previous
//
#include <hip/hip_runtime.h>

#define Bn    256
#define Cc    7
#define Nn    16384
#define HIDW  256
#define SEL   3
#define Mrows (Bn * Cc)            // 1792
#define KSPLIT 16
#define KCHUNK (Nn / KSPLIT)       // 1024
#define BK    32
#define PART_STRIDE ((size_t)Mrows * HIDW)

typedef __attribute__((ext_vector_type(8))) short bf16x8;
typedef __attribute__((ext_vector_type(4))) float floatx4;

#if __has_builtin(__builtin_amdgcn_global_load_lds)
#define HAS_GLDS 1
#endif

// pack high-16 bits of two fp32 words: low ushort = ua>>16, high = ub>>16
__device__ __forceinline__ unsigned pack_hi16(unsigned ua, unsigned ub) {
#if __has_builtin(__builtin_amdgcn_perm)
    return __builtin_amdgcn_perm(ub, ua, 0x07060302u);
#else
    return (ua >> 16) | (ub & 0xffff0000u);
#endif
}

// truncation hi/lo split of a pair of floats -> packed hi word + packed lo word
__device__ __forceinline__ void split2(float a, float b, unsigned& hp, unsigned& lp) {
    unsigned ua = __float_as_uint(a), ub = __float_as_uint(b);
    float fa = __uint_as_float(ua & 0xffff0000u);
    float fb = __uint_as_float(ub & 0xffff0000u);
    float la = a - fa, lb = b - fb;            // exact residuals
    hp = pack_hi16(ua, ub);
    lp = pack_hi16(__float_as_uint(la), __float_as_uint(lb));
}

// ---------------------------------------------------------------------------
// K0: w1[k][n] fp32 -> fragment-ordered bf16 hi/lo planes (trunc split).
// chunk(c,T,lane) holds B[k=c*32+(lane>>4)*8+j][n=T*16+(lane&15)], j=0..7,
// at ushort offset ((c*16+T)*64+lane)*8.
// ---------------------------------------------------------------------------
__global__ __launch_bounds__(256) void convert_w1(const float* __restrict__ w1,
                                                  unsigned short* __restrict__ bhi,
                                                  unsigned short* __restrict__ blo) {
    const int id = blockIdx.x * 256 + threadIdx.x;
    const int l  = id & 63;
    const int ct = id >> 6;
    const int T  = ct & 15;
    const int c  = ct >> 4;
    const int n  = T * 16 + (l & 15);
    const int k  = c * 32 + (l >> 4) * 8;
    float f[8];
#pragma unroll
    for (int j = 0; j < 8; ++j) f[j] = w1[(size_t)(k + j) * HIDW + n];
    unsigned hp[4], lp[4];
#pragma unroll
    for (int m = 0; m < 4; ++m) split2(f[2 * m], f[2 * m + 1], hp[m], lp[m]);
    *(uint4*)(bhi + (size_t)id * 8) = make_uint4(hp[0], hp[1], hp[2], hp[3]);
    *(uint4*)(blo + (size_t)id * 8) = make_uint4(lp[0], lp[1], lp[2], lp[3]);
}

// ---------------------------------------------------------------------------
// K1: MFMA GEMM  part[s][M][256] = feat[M][Kslice] @ w1[Kslice][256]
//     128x128 tile, 4 waves 2x2, 16x16x32 bf16, 3-pass trunc hi/lo split.
//     B staged via global_load_lds (fragment-ordered in global).
// ---------------------------------------------------------------------------
__global__ __launch_bounds__(256) void gemm_mfma(const float* __restrict__ A,
                                                 const unsigned short* __restrict__ Bhi,
                                                 const unsigned short* __restrict__ Blo,
                                                 float* __restrict__ part) {
    __shared__ unsigned short Ah[4096], Al[4096], Bh[4096], Bl[4096];

    const int bx = blockIdx.x;
    const int m0 = blockIdx.y * 128;
    const int s  = blockIdx.z;
    const int k0 = s * KCHUNK;
    const int t  = threadIdx.x;
    const int lane = t & 63;
    const int w    = t >> 6;
    const int wm   = w & 1;
    const int wn   = w >> 1;

    const int ar  = t >> 1;
    const int kof = (t & 1) * 16;
    const float* aptr = A + (size_t)(m0 + ar) * Nn + k0 + kof;
    const int aidx0 = (ar >> 4) * 512 + ((ar & 15) + ((kof >> 3) + 0) * 16) * 8;
    const int aidx1 = (ar >> 4) * 512 + ((ar & 15) + ((kof >> 3) + 1) * 16) * 8;
    const int wbase = (t & 192) * 8;   // wave-uniform LDS ushort base for glds

    floatx4 acc[4][4];
#pragma unroll
    for (int i = 0; i < 4; ++i)
#pragma unroll
        for (int j = 0; j < 4; ++j) acc[i][j] = (floatx4)0.0f;

    for (int kk = 0; kk < KCHUNK; kk += BK) {
        float4 a0 = *(const float4*)(aptr + kk + 0);
        float4 a1 = *(const float4*)(aptr + kk + 4);
        float4 a2 = *(const float4*)(aptr + kk + 8);
        float4 a3 = *(const float4*)(aptr + kk + 12);
        const size_t bbase = ((size_t)(((k0 + kk) >> 5) * 16 + bx * 8)) * 512;

#ifndef HAS_GLDS
        uint4 bh0 = *(const uint4*)(Bhi + bbase + t * 8);
        uint4 bh1 = *(const uint4*)(Bhi + bbase + 2048 + t * 8);
        uint4 bl0 = *(const uint4*)(Blo + bbase + t * 8);
        uint4 bl1 = *(const uint4*)(Blo + bbase + 2048 + t * 8);
#endif
        // trunc hi/lo split of 16 A elements (reg-only, overlaps loads)
        float af[16] = {a0.x, a0.y, a0.z, a0.w, a1.x, a1.y, a1.z, a1.w,
                        a2.x, a2.y, a2.z, a2.w, a3.x, a3.y, a3.z, a3.w};
        unsigned hp[8], lp[8];
#pragma unroll
        for (int m = 0; m < 8; ++m) split2(af[2 * m], af[2 * m + 1], hp[m], lp[m]);

        __syncthreads();   // previous iteration's frag reads complete
#ifdef HAS_GLDS
        __builtin_amdgcn_global_load_lds(
            (const __attribute__((address_space(1))) void*)(Bhi + bbase + t * 8),
            (__attribute__((address_space(3))) void*)&Bh[wbase], 16, 0, 0);
        __builtin_amdgcn_global_load_lds(
            (const __attribute__((address_space(1))) void*)(Bhi + bbase + 2048 + t * 8),
            (__attribute__((address_space(3))) void*)&Bh[2048 + wbase], 16, 0, 0);
        __builtin_amdgcn_global_load_lds(
            (const __attribute__((address_space(1))) void*)(Blo + bbase + t * 8),
            (__attribute__((address_space(3))) void*)&Bl[wbase], 16, 0, 0);
        __builtin_amdgcn_global_load_lds(
            (const __attribute__((address_space(1))) void*)(Blo + bbase + 2048 + t * 8),
            (__attribute__((address_space(3))) void*)&Bl[2048 + wbase], 16, 0, 0);
#else
        *(uint4*)&Bh[t * 8]        = bh0;
        *(uint4*)&Bh[2048 + t * 8] = bh1;
        *(uint4*)&Bl[t * 8]        = bl0;
        *(uint4*)&Bl[2048 + t * 8] = bl1;
#endif
        *(uint4*)&Ah[aidx0] = make_uint4(hp[0], hp[1], hp[2], hp[3]);
        *(uint4*)&Ah[aidx1] = make_uint4(hp[4], hp[5], hp[6], hp[7]);
        *(uint4*)&Al[aidx0] = make_uint4(lp[0], lp[1], lp[2], lp[3]);
        *(uint4*)&Al[aidx1] = make_uint4(lp[4], lp[5], lp[6], lp[7]);
        __syncthreads();

        bf16x8 fah[4], fal[4], fbh[4], fbl[4];
#pragma unroll
        for (int i = 0; i < 4; ++i) {
            fah[i] = *(const bf16x8*)&Ah[(wm * 4 + i) * 512 + lane * 8];
            fal[i] = *(const bf16x8*)&Al[(wm * 4 + i) * 512 + lane * 8];
        }
#pragma unroll
        for (int j = 0; j < 4; ++j) {
            fbh[j] = *(const bf16x8*)&Bh[(wn * 4 + j) * 512 + lane * 8];
            fbl[j] = *(const bf16x8*)&Bl[(wn * 4 + j) * 512 + lane * 8];
        }
#pragma unroll
        for (int i = 0; i < 4; ++i)
#pragma unroll
            for (int j = 0; j < 4; ++j) {
                acc[i][j] = __builtin_amdgcn_mfma_f32_16x16x32_bf16(fah[i], fbh[j], acc[i][j], 0, 0, 0);
                acc[i][j] = __builtin_amdgcn_mfma_f32_16x16x32_bf16(fah[i], fbl[j], acc[i][j], 0, 0, 0);
                acc[i][j] = __builtin_amdgcn_mfma_f32_16x16x32_bf16(fal[i], fbh[j], acc[i][j], 0, 0, 0);
            }
    }

    const int row4 = (lane >> 4) * 4;
    const int col  = lane & 15;
    float* base = part + (size_t)s * PART_STRIDE;
#pragma unroll
    for (int i = 0; i < 4; ++i)
#pragma unroll
        for (int j = 0; j < 4; ++j) {
            const int n = bx * 128 + wn * 64 + j * 16 + col;
#pragma unroll
            for (int p = 0; p < 4; ++p) {
                const int m = m0 + wm * 64 + i * 16 + row4 + p;
                base[(size_t)m * HIDW + n] = acc[i][j][p];
            }
        }
}

// ---------------------------------------------------------------------------
// K2: one block per row — reduce KSPLIT partials, relu, dot w2 -> scores[row]
// (b2 omitted: constant shift doesn't change ordering)
// ---------------------------------------------------------------------------
__global__ __launch_bounds__(256) void score_rows(const float* __restrict__ part,
                                                  const float* __restrict__ b1,
                                                  const float* __restrict__ w2,
                                                  float* __restrict__ scores) {
    const int r = blockIdx.x;
    const int t = threadIdx.x;
    const size_t off = (size_t)r * HIDW + t;
    float h = 0.0f;
#pragma unroll
    for (int s = 0; s < KSPLIT; ++s) h += part[(size_t)s * PART_STRIDE + off];
    float p = fmaxf(h + b1[t], 0.0f) * w2[t];
#pragma unroll
    for (int o = 32; o > 0; o >>= 1) p += __shfl_down(p, o, 64);
    __shared__ float red[4];
    if ((t & 63) == 0) red[t >> 6] = p;
    __syncthreads();
    if (t == 0) scores[r] = red[0] + red[1] + red[2] + red[3];
}

// ---------------------------------------------------------------------------
// K3: one thread per batch — top-3 of 7, write index floats + sidx
// ---------------------------------------------------------------------------
__global__ __launch_bounds__(256) void topk_kernel(const float* __restrict__ scores,
                                                   float* __restrict__ out,
                                                   int* __restrict__ sidx) {
    const int b = threadIdx.x;
    float sc[Cc];
#pragma unroll
    for (int c = 0; c < Cc; ++c) sc[c] = scores[b * Cc + c];
    bool used[Cc] = {};
#pragma unroll
    for (int k = 0; k < SEL; ++k) {
        int best = 0;
        float bv = -3.4e38f;
#pragma unroll
        for (int c = 0; c < Cc; ++c)
            if (!used[c] && sc[c] > bv) { bv = sc[c]; best = c; }
        used[best] = true;
        sidx[b * SEL + k] = best;
        out[(size_t)Bn * SEL * Nn + b * SEL + k] = (float)best;
    }
}

// ---------------------------------------------------------------------------
// K4: gather — one block per (batch, sel)
// ---------------------------------------------------------------------------
__global__ __launch_bounds__(256) void gather_bands(const float* __restrict__ x,
                                                    const int* __restrict__ sidx,
                                                    float* __restrict__ out) {
    const int id = blockIdx.x;
    const int b  = id / SEL;
    const int band = sidx[id];
    const float4* src = (const float4*)(x + (size_t)(b * Cc + band) * Nn);
    float4* dst = (float4*)(out + (size_t)id * Nn);
    for (int i = threadIdx.x; i < Nn / 4; i += 256) dst[i] = src[i];
}

// ---------------------------------------------------------------------------
extern "C" void kernel_launch(void* const* d_in, const int* in_sizes, int n_in,
                              void* d_out, int out_size, void* d_ws, size_t ws_size,
                              hipStream_t stream) {
    const float* x  = (const float*)d_in[0];
    // d_in[1]=w_qkv, d_in[2]=b_qkv: dead in the reference forward
    const float* w1 = (const float*)d_in[3];
    const float* b1 = (const float*)d_in[4];
    const float* w2 = (const float*)d_in[5];
    const float* b2 = (const float*)d_in[6];
    (void)b2;
    float* out = (float*)d_out;

    char* ws = (char*)d_ws;
    float* part = (float*)ws;                                            // 29.36 MB
    unsigned short* bhi = (unsigned short*)(ws + KSPLIT * PART_STRIDE * sizeof(float));
    unsigned short* blo = bhi + (size_t)Nn * HIDW;                       // 8 MB each
    int*   sidx   = (int*)(blo + (size_t)Nn * HIDW);
    float* scores = (float*)(sidx + Bn * SEL);

    convert_w1<<<(Nn / 32) * 16 * 64 / 256, 256, 0, stream>>>(w1, bhi, blo);
    gemm_mfma<<<dim3(HIDW / 128, Mrows / 128, KSPLIT), 256, 0, stream>>>(x, bhi, blo, part);
    score_rows<<<Mrows, 256, 0, stream>>>(part, b1, w2, scores);
    topk_kernel<<<1, 256, 0, stream>>>(scores, out, sidx);
    gather_bands<<<Bn * SEL, 256, 0, stream>>>(x, sidx, out);
}